// Round 15
// baseline (109.549 us; speedup 1.0000x reference)
//
#include <hip/hip_runtime.h>
#include <hip/hip_bf16.h>
#include <math.h>

#define BB 32
#define TT 2048
#define FF 512
#define UU 512

typedef __attribute__((ext_vector_type(4))) float f32x4;
typedef __attribute__((ext_vector_type(4))) short bf16x4;
typedef __attribute__((ext_vector_type(8))) short bf16x8;

__device__ inline short f2bf(float f) {
  union { __hip_bfloat16 h; short s; } u;
  u.h = __float2bfloat16(f);
  return u.s;
}

__device__ inline float bf2f(unsigned short s) {
  return __uint_as_float(((unsigned)s) << 16);
}

// tanh(x) = 1 - 2/(exp(2x)+1). ~6 VALU ops, ~1e-6 abs err, saturates right.
__device__ inline float tanh_fast(float x) {
  float e = __expf(2.0f * x);
  return 1.0f - 2.0f * __builtin_amdgcn_rcpf(e + 1.0f);
}

// ws layout (floats) -- no memset needed; every buffer fully written:
// hw:     [0,       16384)
// mbuf:   [16384,   17408)   32 b x 32 tiles
// lbuf:   [17408,   18432)
// cpart:  [18432,   542720)  32 b x 32 tiles x 512 f (f32)
// Gp:     [542720,  935936)  8 ksl x 32 b x 1536 n
// qp:     [935936,  1067008) 8 ksl x 32 b x 512 u
// Up:     shorts at float-offset 1067008 (262144 shorts = 512 KB)

// Fused k0_pack + k1_hw (independent work, concurrent).
__global__ __launch_bounds__(256) void k01(
    const float* __restrict__ Ua, short* __restrict__ Up,
    const float* __restrict__ h, const float* __restrict__ Wa,
    const float* __restrict__ Wa_bias, const float* __restrict__ Ua_bias,
    float* __restrict__ hw) {
  const int bid = blockIdx.x;
  const int tid = threadIdx.x;
  if (bid < 128) {
    const int cell = bid * 4 + (tid >> 6);   // 0..511 = n16*16 + k32
    const int n16 = cell >> 4;
    const int k32 = cell & 15;
    const int l = tid & 63;
    const int n = n16 * 16 + (l & 15);
    const int g = l >> 4;
    bf16x8 v;
#pragma unroll
    for (int i = 0; i < 8; ++i) {
      int k = k32 * 32 + (i < 4 ? g * 4 + i : 16 + g * 4 + (i - 4));
      v[i] = f2bf(Ua[k * UU + n]);
    }
    *reinterpret_cast<bf16x8*>(Up + ((size_t)cell * 64 + l) * 8) = v;
  } else {
    int idx = (bid - 128) * 256 + tid;  // 16384 = B*U
    int b = idx >> 9;
    int u = idx & 511;
    float acc = Wa_bias[u] + Ua_bias[u];
    const float* hrow = h + b * UU;
#pragma unroll 8
    for (int f = 0; f < FF; ++f) acc += hrow[f] * Wa[f * UU + u];
    hw[idx] = acc;
  }
}

// Flash kernel v10: t-tile = 64, chunk-pipelined stage + counted barriers,
// LDS ~75 KB -> 2 blocks/CU (cross-block phase overlap). 512 threads, 8
// waves; wave w owns u-slice [64w, 64w+64): mf 0..3, nf 0..3 (acc 64 reg).
// Staging: wave pair (2*mf, 2*mf+1) splits each 16B fragment cell; per
// thread per slot: one f32x4 load + one 8B LDS write.
__global__ __launch_bounds__(512, 4) void k2_flash(
    const float* __restrict__ ann, const short* __restrict__ Up,
    const float* __restrict__ Va, const float* __restrict__ hw,
    float* __restrict__ mbuf, float* __restrict__ lbuf,
    float* __restrict__ cpart) {
  __shared__ short Af[32768];      // 64 fb x 64 slot x 8 bf16 = 64 KB
  __shared__ float red[8][64];     // 2 KB
  __shared__ float e_all[64];
  __shared__ float ctxp[4][512];   // 8 KB
  const int tile = blockIdx.x;     // 0..31
  const int b = blockIdx.y;
  const int t0 = tile * 64;
  const int tid = threadIdx.x;     // 0..511
  const int w = tid >> 6;          // wave 0..7
  const int l = tid & 63;
  const int lo = l & 15;
  const int g = l >> 4;
  const int mfs = w >> 1;          // staging row-block
  const int hh = w & 1;            // staging half of the 16B cell

  const float* annb = ann + ((size_t)b * TT + t0) * FF;
  const float* srow = annb + (size_t)(mfs * 16 + lo) * FF + hh * 16 + g * 4;
  short* const afw = &Af[mfs * 8192 + l * 8 + hh * 4];

  const short* upb[4];
  upb[0] = Up + ((size_t)((w * 4 + 0) * 16) * 64 + l) * 8;
  upb[1] = Up + ((size_t)((w * 4 + 1) * 16) * 64 + l) * 8;
  upb[2] = Up + ((size_t)((w * 4 + 2) * 16) * 64 + l) * 8;
  upb[3] = Up + ((size_t)((w * 4 + 3) * 16) * 64 + l) * 8;

  f32x4 acc[4][4];
#pragma unroll
  for (int mf = 0; mf < 4; ++mf)
#pragma unroll
    for (int nf = 0; nf < 4; ++nf) acc[mf][nf] = (f32x4)0.f;

  f32x4 stg[2];
  bf16x8 bb[2][4];

  // ---- prologue: load chunks 0,1; write chunk 0; B slots 0,1 ----
  stg[0] = *reinterpret_cast<const f32x4*>(srow + 0 * 32);
  stg[1] = *reinterpret_cast<const f32x4*>(srow + 1 * 32);
#pragma unroll
  for (int nf = 0; nf < 4; ++nf) {
    bb[0][nf] = *reinterpret_cast<const bf16x8*>(upb[nf]);
    bb[1][nf] = *reinterpret_cast<const bf16x8*>(upb[nf] + 512);
  }
  {
    bf16x4 o;
    o[0] = f2bf(stg[0].x); o[1] = f2bf(stg[0].y);
    o[2] = f2bf(stg[0].z); o[3] = f2bf(stg[0].w);
    *reinterpret_cast<bf16x4*>(afw) = o;
  }
  __syncthreads();

  // ---- pipelined main loop over 16 k-slots ----
#pragma unroll
  for (int s = 0; s < 16; ++s) {
    if (s < 14)
      stg[s & 1] = *reinterpret_cast<const f32x4*>(srow + (s + 2) * 32);
    __builtin_amdgcn_s_setprio(1);
#pragma unroll
    for (int mf = 0; mf < 4; ++mf) {
      bf16x8 a = *reinterpret_cast<const bf16x8*>(
          &Af[mf * 8192 + s * 512 + l * 8]);
#pragma unroll
      for (int nf = 0; nf < 4; ++nf)
        acc[mf][nf] = __builtin_amdgcn_mfma_f32_16x16x32_bf16(
            a, bb[s & 1][nf], acc[mf][nf], 0, 0, 0);
    }
    __builtin_amdgcn_s_setprio(0);
    if (s < 14) {
#pragma unroll
      for (int nf = 0; nf < 4; ++nf)
        bb[s & 1][nf] =
            *reinterpret_cast<const bf16x8*>(upb[nf] + (s + 2) * 512);
    }
    if (s < 15) {
      const f32x4 c0 = stg[(s + 1) & 1];
      bf16x4 o;
      o[0] = f2bf(c0.x); o[1] = f2bf(c0.y);
      o[2] = f2bf(c0.z); o[3] = f2bf(c0.w);
      *reinterpret_cast<bf16x4*>(afw + (s + 1) * 512) = o;
      asm volatile("s_waitcnt lgkmcnt(0)" ::: "memory");
      __builtin_amdgcn_s_barrier();
    }
  }
  __syncthreads();

  // ---- scores epilogue: tanh(acc + hw[u]) * Va[u], reduce over u ----
  const float* hwb = hw + b * UU;
  float part[4][4];
#pragma unroll
  for (int mf = 0; mf < 4; ++mf)
#pragma unroll
    for (int r = 0; r < 4; ++r) part[mf][r] = 0.f;
#pragma unroll
  for (int nf = 0; nf < 4; ++nf) {
    const int u = w * 64 + nf * 16 + lo;
    const float hv = hwb[u];
    const float vv = Va[u];
#pragma unroll
    for (int mf = 0; mf < 4; ++mf)
#pragma unroll
      for (int r = 0; r < 4; ++r)
        part[mf][r] += tanh_fast(acc[mf][nf][r] + hv) * vv;
  }
#pragma unroll
  for (int mf = 0; mf < 4; ++mf)
#pragma unroll
    for (int r = 0; r < 4; ++r) {
      float s = part[mf][r];
      s += __shfl_xor(s, 1);
      s += __shfl_xor(s, 2);
      s += __shfl_xor(s, 4);
      s += __shfl_xor(s, 8);
      part[mf][r] = s;
    }
  if (lo == 0) {
#pragma unroll
    for (int mf = 0; mf < 4; ++mf)
#pragma unroll
      for (int r = 0; r < 4; ++r)
        red[w][mf * 16 + g * 4 + r] = part[mf][r];
  }
  __syncthreads();

  // ---- tile softmax stats over 64 rows (wave 0) ----
  if (tid < 64) {
    float s = red[0][tid] + red[1][tid] + red[2][tid] + red[3][tid] +
              red[4][tid] + red[5][tid] + red[6][tid] + red[7][tid];
    float m = s;
#pragma unroll
    for (int off = 1; off < 64; off <<= 1) m = fmaxf(m, __shfl_xor(m, off));
    float e = __expf(s - m);
    e_all[tid] = e;
    float ls = e;
#pragma unroll
    for (int off = 1; off < 64; off <<= 1) ls += __shfl_xor(ls, off);
    if (tid == 0) {
      mbuf[b * 32 + tile] = m;
      lbuf[b * 32 + tile] = ls;
    }
  }
  __syncthreads();

  // ---- partial context: 64 f-owners x 4 t-slices of 16 rows ----
  if (tid < 256) {
    const int fo = tid & 63;
    const int ts = tid >> 6;         // 0..3
    const int kk2 = fo >> 2;
    const int gg = fo & 3;
    float a8[8];
#pragma unroll
    for (int j = 0; j < 8; ++j) a8[j] = 0.f;
#pragma unroll
    for (int it = 0; it < 16; ++it) {
      const int tl = (it + fo) & 15;
      const int t = ts * 16 + tl;
      const int entry = ((t >> 4) * 16 + kk2) * 64 + gg * 16 + tl;
      bf16x8 v = *reinterpret_cast<const bf16x8*>(&Af[entry * 8]);
      const float e = e_all[t];
#pragma unroll
      for (int j = 0; j < 8; ++j)
        a8[j] += e * bf2f((unsigned short)v[j]);
    }
#pragma unroll
    for (int j = 0; j < 8; ++j) ctxp[ts][fo * 8 + j] = a8[j];
  }
  __syncthreads();
  {
    float s = ctxp[0][tid] + ctxp[1][tid] + ctxp[2][tid] + ctxp[3][tid];
    const int fo2 = tid >> 3;
    const int j2 = tid & 7;
    const int f = (fo2 >> 2) * 32 +
                  ((j2 < 4) ? (fo2 & 3) * 4 + j2 : 16 + (fo2 & 3) * 4 + (j2 - 4));
    cpart[(size_t)(b * 32 + tile) * 512 + f] = s;
  }
}

// --- gate GEMM with fused context combine (32 tiles/b) --------------------
__global__ __launch_bounds__(512) void k5a_gates(
    const float* __restrict__ x, const float* __restrict__ mbuf,
    const float* __restrict__ lbuf, const float* __restrict__ cpart,
    const float* __restrict__ h, const float* __restrict__ kern,
    const float* __restrict__ ak, const float* __restrict__ rk,
    float* __restrict__ Gp) {
  __shared__ float wsx[64][64], wsa[64][64], wsr[64][64];
  __shared__ float xs[32][64], cs[32][64], hs[32][64];
  __shared__ float lsm[1024], lsl[1024], lwinv[1024];
  const int n0 = blockIdx.x * 64;
  const int kg = blockIdx.y;
  const int kg0 = kg * 64;
  const bool has_r = (n0 < 1024);
  const int tid = threadIdx.x;
  const int n = tid & 63;
  const int b0 = (tid >> 6) * 4;
  const int wrow = tid >> 3, wcol = (tid & 7) * 8;
  const int orow = tid >> 4, ocol = (tid & 15) * 4;
  float acc[4] = {0.f, 0.f, 0.f, 0.f};

  lsm[tid] = mbuf[tid];
  lsm[tid + 512] = mbuf[tid + 512];
  lsl[tid] = lbuf[tid];
  lsl[tid + 512] = lbuf[tid + 512];

  {
    const size_t wb = (size_t)(kg0 + wrow) * 1536 + n0 + wcol;
    *reinterpret_cast<float4*>(&wsx[wrow][wcol])     = *reinterpret_cast<const float4*>(kern + wb);
    *reinterpret_cast<float4*>(&wsx[wrow][wcol + 4]) = *reinterpret_cast<const float4*>(kern + wb + 4);
    *reinterpret_cast<float4*>(&wsa[wrow][wcol])     = *reinterpret_cast<const float4*>(ak + wb);
    *reinterpret_cast<float4*>(&wsa[wrow][wcol + 4]) = *reinterpret_cast<const float4*>(ak + wb + 4);
    if (has_r) {
      *reinterpret_cast<float4*>(&wsr[wrow][wcol])     = *reinterpret_cast<const float4*>(rk + wb);
      *reinterpret_cast<float4*>(&wsr[wrow][wcol + 4]) = *reinterpret_cast<const float4*>(rk + wb + 4);
    }
    *reinterpret_cast<float4*>(&xs[orow][ocol]) =
        *reinterpret_cast<const float4*>(x + orow * FF + kg0 + ocol);
    *reinterpret_cast<float4*>(&hs[orow][ocol]) =
        *reinterpret_cast<const float4*>(h + orow * UU + kg0 + ocol);
  }
  __syncthreads();

  // winv[b][i] = exp(m_i - M_b) / D_b
  if (tid < 32) {
    float M = -1e30f;
#pragma unroll
    for (int i = 0; i < 32; ++i) M = fmaxf(M, lsm[tid * 32 + i]);
    float D = 0.f;
#pragma unroll
    for (int i = 0; i < 32; ++i)
      D += __expf(lsm[tid * 32 + i] - M) * lsl[tid * 32 + i];
    const float inv = 1.f / D;
#pragma unroll
    for (int i = 0; i < 32; ++i)
      lwinv[tid * 32 + i] = __expf(lsm[tid * 32 + i] - M) * inv;
  }
  __syncthreads();

  // cs[orow][ocol..+3] = c[orow][kg0+ocol..+3]
  {
    float4 cv = {0.f, 0.f, 0.f, 0.f};
#pragma unroll
    for (int i = 0; i < 32; ++i) {
      const float wi = lwinv[orow * 32 + i];
      const float4 cp = *reinterpret_cast<const float4*>(
          &cpart[(size_t)(orow * 32 + i) * 512 + kg0 + ocol]);
      cv.x += wi * cp.x; cv.y += wi * cp.y;
      cv.z += wi * cp.z; cv.w += wi * cp.w;
    }
    *reinterpret_cast<float4*>(&cs[orow][ocol]) = cv;
  }
  __syncthreads();

  if (has_r) {
#pragma unroll 8
    for (int k = 0; k < 64; ++k) {
      const float wx = wsx[k][n], wa = wsa[k][n], wr = wsr[k][n];
#pragma unroll
      for (int j = 0; j < 4; ++j)
        acc[j] += xs[b0 + j][k] * wx + cs[b0 + j][k] * wa + hs[b0 + j][k] * wr;
    }
  } else {
#pragma unroll 8
    for (int k = 0; k < 64; ++k) {
      const float wx = wsx[k][n], wa = wsa[k][n];
#pragma unroll
      for (int j = 0; j < 4; ++j)
        acc[j] += xs[b0 + j][k] * wx + cs[b0 + j][k] * wa;
    }
  }
#pragma unroll
  for (int j = 0; j < 4; ++j)
    Gp[(size_t)kg * 49152 + (size_t)(b0 + j) * 1536 + n0 + n] = acc[j];
}

// k5c with fused r-gate: rs computed inline from Gp sums.
__global__ __launch_bounds__(512) void k5c_q(
    const float* __restrict__ Gp, const float* __restrict__ h,
    const float* __restrict__ bias, const float* __restrict__ abias,
    const float* __restrict__ rk, float* __restrict__ qp) {
  __shared__ float wsr[64][64];
  __shared__ float rs[32][64];
  const int n0 = blockIdx.x * 64;
  const int kg = blockIdx.y;
  const int kg0 = kg * 64;
  const int tid = threadIdx.x;
  const int n = tid & 63;
  const int b0 = (tid >> 6) * 4;
  const int wrow = tid >> 3, wcol = (tid & 7) * 8;
  const int orow = tid >> 4, ocol = (tid & 15) * 4;
  float acc[4] = {0.f, 0.f, 0.f, 0.f};

  {
    const size_t wb = (size_t)(kg0 + wrow) * 1536 + 1024 + n0 + wcol;
    *reinterpret_cast<float4*>(&wsr[wrow][wcol])     = *reinterpret_cast<const float4*>(rk + wb);
    *reinterpret_cast<float4*>(&wsr[wrow][wcol + 4]) = *reinterpret_cast<const float4*>(rk + wb + 4);
  }
  {
    const int u = kg0 + ocol;
    float4 sr = *reinterpret_cast<const float4*>(bias + 512 + u);
    const float4 ab = *reinterpret_cast<const float4*>(abias + 512 + u);
    sr.x += ab.x; sr.y += ab.y; sr.z += ab.z; sr.w += ab.w;
#pragma unroll
    for (int p = 0; p < 8; ++p) {
      const float4 gp4 = *reinterpret_cast<const float4*>(
          Gp + (size_t)p * 49152 + (size_t)orow * 1536 + 512 + u);
      sr.x += gp4.x; sr.y += gp4.y; sr.z += gp4.z; sr.w += gp4.w;
    }
    const float4 hv = *reinterpret_cast<const float4*>(h + orow * UU + u);
    rs[orow][ocol]     = fminf(fmaxf(0.2f * sr.x + 0.5f, 0.f), 1.f) * hv.x;
    rs[orow][ocol + 1] = fminf(fmaxf(0.2f * sr.y + 0.5f, 0.f), 1.f) * hv.y;
    rs[orow][ocol + 2] = fminf(fmaxf(0.2f * sr.z + 0.5f, 0.f), 1.f) * hv.z;
    rs[orow][ocol + 3] = fminf(fmaxf(0.2f * sr.w + 0.5f, 0.f), 1.f) * hv.w;
  }
  __syncthreads();
#pragma unroll 8
  for (int k = 0; k < 64; ++k) {
    const float w = wsr[k][n];
#pragma unroll
    for (int j = 0; j < 4; ++j) acc[j] += rs[b0 + j][k] * w;
  }
#pragma unroll
  for (int j = 0; j < 4; ++j)
    qp[(size_t)kg * 16384 + (b0 + j) * UU + n0 + n] = acc[j];
}

// k5d: z and hh from summed partials.
__global__ __launch_bounds__(256) void k5d_out(
    const float* __restrict__ Gp, const float* __restrict__ qp,
    const float* __restrict__ h, const float* __restrict__ bias,
    const float* __restrict__ abias, float* __restrict__ out) {
  int idx = blockIdx.x * blockDim.x + threadIdx.x;  // 16384
  int b = idx >> 9;
  int u = idx & 511;
  float sz = bias[u] + abias[u];
  float sh = bias[1024 + u] + abias[1024 + u];
  const float* gb = Gp + (size_t)b * 1536;
  const float* qb = qp + (size_t)b * 512;
#pragma unroll
  for (int p = 0; p < 8; ++p) {
    sz += gb[(size_t)p * 49152 + u];
    sh += gb[(size_t)p * 49152 + 1024 + u] + qb[(size_t)p * 16384 + u];
  }
  float z = fminf(fmaxf(0.2f * sz + 0.5f, 0.f), 1.f);
  float hh = tanhf(sh);
  out[idx] = z * h[idx] + (1.f - z) * hh;
}

extern "C" void kernel_launch(void* const* d_in, const int* in_sizes, int n_in,
                              void* d_out, int out_size, void* d_ws, size_t ws_size,
                              hipStream_t stream) {
  const float* x       = (const float*)d_in[0];
  const float* h       = (const float*)d_in[1];
  const float* ann     = (const float*)d_in[2];
  const float* kern    = (const float*)d_in[3];
  const float* rk      = (const float*)d_in[4];
  const float* ak      = (const float*)d_in[5];
  const float* Wa      = (const float*)d_in[6];
  const float* Ua      = (const float*)d_in[7];
  const float* Va      = (const float*)d_in[8];
  const float* bias    = (const float*)d_in[9];
  const float* abias   = (const float*)d_in[10];
  const float* Wa_bias = (const float*)d_in[11];
  const float* Ua_bias = (const float*)d_in[12];

  float* ws     = (float*)d_ws;
  float* hw     = ws;             // 16384
  float* mbuf   = ws + 16384;     // 1024
  float* lbuf   = ws + 17408;     // 1024
  float* cpart  = ws + 18432;     // 524288
  float* Gp     = ws + 542720;    // 393216 (8 x 32 x 1536)
  float* qp     = ws + 935936;    // 131072 (8 x 32 x 512)
  short* Up     = (short*)(ws + 1067008);  // 262144 shorts

  k01<<<192, 256, 0, stream>>>(Ua, Up, h, Wa, Wa_bias, Ua_bias, hw);

  dim3 g2(TT / 64, BB);
  k2_flash<<<g2, 512, 0, stream>>>(ann, Up, Va, hw, mbuf, lbuf, cpart);

  dim3 g5a(24, 8);
  k5a_gates<<<g5a, 512, 0, stream>>>(x, mbuf, lbuf, cpart, h, kern, ak, rk, Gp);

  dim3 g5c(8, 8);
  k5c_q<<<g5c, 512, 0, stream>>>(Gp, h, bias, abias, rk, qp);

  k5d_out<<<64, 256, 0, stream>>>(Gp, qp, h, bias, abias, (float*)d_out);
}

// Round 16
// 103.375 us; speedup vs baseline: 1.0597x; 1.0597x over previous
//
#include <hip/hip_runtime.h>
#include <hip/hip_bf16.h>
#include <math.h>

#define BB 32
#define TT 2048
#define FF 512
#define UU 512

typedef __attribute__((ext_vector_type(4))) float f32x4;
typedef __attribute__((ext_vector_type(4))) short bf16x4;
typedef __attribute__((ext_vector_type(8))) short bf16x8;

__device__ inline short f2bf(float f) {
  union { __hip_bfloat16 h; short s; } u;
  u.h = __float2bfloat16(f);
  return u.s;
}

__device__ inline float bf2f(unsigned short s) {
  return __uint_as_float(((unsigned)s) << 16);
}

// tanh(x) = 1 - 2/(exp(2x)+1). ~6 VALU ops, ~1e-6 abs err, saturates right.
__device__ inline float tanh_fast(float x) {
  float e = __expf(2.0f * x);
  return 1.0f - 2.0f * __builtin_amdgcn_rcpf(e + 1.0f);
}

// ws layout (floats) -- no memset needed; every buffer fully written:
// hw:     [0,      16384)
// mbuf:   [16384,  16896)    32 b x 16 tiles
// lbuf:   [16896,  17408)
// cpart:  [17408,  279552)   32 b x 16 tiles x 512 f (f32)
// Gp:     [279552, 672768)   8 ksl x 32 b x 1536 n  (non-atomic partials)
// qp:     [672768, 803840)   8 ksl x 32 b x 512 u
// Up:     shorts at float-offset 803840 (262144 shorts = 512 KB)

__global__ __launch_bounds__(256) void k1_hw(
    const float* __restrict__ h, const float* __restrict__ Wa,
    const float* __restrict__ Wa_bias, const float* __restrict__ Ua_bias,
    float* __restrict__ hw) {
  int idx = blockIdx.x * blockDim.x + threadIdx.x;  // 16384 = B*U
  int b = idx >> 9;
  int u = idx & 511;
  float acc = Wa_bias[u] + Ua_bias[u];
  const float* hrow = h + b * UU;
#pragma unroll 8
  for (int f = 0; f < FF; ++f) acc += hrow[f] * Wa[f * UU + u];
  hw[idx] = acc;
}

// Pack Ua (fp32 [k][n]) into fragment-native bf16 layout.
__global__ __launch_bounds__(64) void k0_pack(
    const float* __restrict__ Ua, short* __restrict__ Up) {
  const int n16 = blockIdx.x;   // 0..31
  const int k32 = blockIdx.y;   // 0..15
  const int l = threadIdx.x;    // 0..63
  const int n = n16 * 16 + (l & 15);
  const int g = l >> 4;
  bf16x8 v;
#pragma unroll
  for (int i = 0; i < 8; ++i) {
    int k = k32 * 32 + (i < 4 ? g * 4 + i : 16 + g * 4 + (i - 4));
    v[i] = f2bf(Ua[k * UU + n]);
  }
  *reinterpret_cast<bf16x8*>(Up + ((size_t)(n16 * 16 + k32) * 64 + l) * 8) = v;
}

// Flash kernel v11 = R13 champion with PAIRED barriers: chunks s+1,s+2 are
// written together at odd s, so the counted-wait barrier runs once per TWO
// k-slots (7 barriers vs 15). Staging depth: 4 chunks in flight (stg[4][2],
// parity indices constant after full unroll; prefetch distance ~3 slots).
__global__ __launch_bounds__(512, 2) void k2_flash(
    const float* __restrict__ ann, const short* __restrict__ Up,
    const float* __restrict__ Va, const float* __restrict__ hw,
    float* __restrict__ mbuf, float* __restrict__ lbuf,
    float* __restrict__ cpart) {
  __shared__ short Af[65536];      // 128 fb x 64 lane x 8 bf16 = 128 KB
  __shared__ float red[8][128];    // 4 KB
  __shared__ float e_all[128];
  __shared__ float sred[128];
  __shared__ float wtmp[4];
  __shared__ float ctxp[8][512];   // 16 KB
  const int tile = blockIdx.x;     // 0..15
  const int b = blockIdx.y;
  const int t0 = tile * 128;
  const int tid = threadIdx.x;     // 0..511
  const int w = tid >> 6;          // wave 0..7
  const int l = tid & 63;
  const int lo = l & 15;
  const int g = l >> 4;

  const float* annb = ann + ((size_t)b * TT + t0) * FF;
  // this thread's staging source row (fixed): wave w stages rows w*16+lo
  const float* srow = annb + (size_t)(w * 16 + lo) * FF + g * 4;
  // this thread's staging LDS entry base for chunk s: E = (w*16+s)*64 + l
  short* const afw = &Af[((w * 16) * 64 + l) * 8];

  const short* upb[4];
  upb[0] = Up + ((size_t)((w * 4 + 0) * 16) * 64 + l) * 8;
  upb[1] = Up + ((size_t)((w * 4 + 1) * 16) * 64 + l) * 8;
  upb[2] = Up + ((size_t)((w * 4 + 2) * 16) * 64 + l) * 8;
  upb[3] = Up + ((size_t)((w * 4 + 3) * 16) * 64 + l) * 8;

  f32x4 acc[8][4];
#pragma unroll
  for (int mf = 0; mf < 8; ++mf)
#pragma unroll
    for (int nf = 0; nf < 4; ++nf) acc[mf][nf] = (f32x4)0.f;

  // 4 chunks in flight, parity-indexed (constant indices after unroll)
  f32x4 stg[4][2];
  bf16x8 bb[2][4];

  // ---- prologue: load chunks 0-3; write chunks 0,1; B slots 0,1 ----
#pragma unroll
  for (int c = 0; c < 4; ++c) {
    stg[c][0] = *reinterpret_cast<const f32x4*>(srow + c * 32);
    stg[c][1] = *reinterpret_cast<const f32x4*>(srow + c * 32 + 16);
  }
#pragma unroll
  for (int nf = 0; nf < 4; ++nf) {
    bb[0][nf] = *reinterpret_cast<const bf16x8*>(upb[nf]);
    bb[1][nf] = *reinterpret_cast<const bf16x8*>(upb[nf] + 512);
  }
#pragma unroll
  for (int c = 0; c < 2; ++c) {
    bf16x8 o;
    o[0] = f2bf(stg[c][0].x); o[1] = f2bf(stg[c][0].y);
    o[2] = f2bf(stg[c][0].z); o[3] = f2bf(stg[c][0].w);
    o[4] = f2bf(stg[c][1].x); o[5] = f2bf(stg[c][1].y);
    o[6] = f2bf(stg[c][1].z); o[7] = f2bf(stg[c][1].w);
    *reinterpret_cast<bf16x8*>(afw + c * 512) = o;
  }
  __syncthreads();

  // ---- pipelined main loop over k-slots, barrier every 2 slots ----
#pragma unroll
  for (int s = 0; s < 16; ++s) {
    // even s: issue loads for chunks s+4, s+5 (freed at barrier s-1)
    if ((s & 1) == 0 && s <= 10) {
      stg[s & 3][0] = *reinterpret_cast<const f32x4*>(srow + (s + 4) * 32);
      stg[s & 3][1] = *reinterpret_cast<const f32x4*>(srow + (s + 4) * 32 + 16);
      stg[(s + 1) & 3][0] = *reinterpret_cast<const f32x4*>(srow + (s + 5) * 32);
      stg[(s + 1) & 3][1] = *reinterpret_cast<const f32x4*>(srow + (s + 5) * 32 + 16);
    }
    // A fragments for slot s
    bf16x8 aA[8];
#pragma unroll
    for (int mf = 0; mf < 8; ++mf)
      aA[mf] = *reinterpret_cast<const bf16x8*>(
          &Af[((mf * 16 + s) * 64 + l) * 8]);
    __builtin_amdgcn_s_setprio(1);
#pragma unroll
    for (int mf = 0; mf < 8; ++mf)
#pragma unroll
      for (int nf = 0; nf < 4; ++nf)
        acc[mf][nf] = __builtin_amdgcn_mfma_f32_16x16x32_bf16(
            aA[mf], bb[s & 1][nf], acc[mf][nf], 0, 0, 0);
    __builtin_amdgcn_s_setprio(0);
    // refill B slot s+2 into bb[s&1] (just consumed)
    if (s < 14) {
#pragma unroll
      for (int nf = 0; nf < 4; ++nf)
        bb[s & 1][nf] =
            *reinterpret_cast<const bf16x8*>(upb[nf] + (s + 2) * 512);
    }
    // odd s: write chunks s+1, s+2; one barrier per pair
    if ((s & 1) == 1 && s <= 13) {
#pragma unroll
      for (int d = 1; d <= 2; ++d) {
        const f32x4 c0 = stg[(s + d) & 3][0];
        const f32x4 c1 = stg[(s + d) & 3][1];
        bf16x8 o;
        o[0] = f2bf(c0.x); o[1] = f2bf(c0.y); o[2] = f2bf(c0.z); o[3] = f2bf(c0.w);
        o[4] = f2bf(c1.x); o[5] = f2bf(c1.y); o[6] = f2bf(c1.z); o[7] = f2bf(c1.w);
        *reinterpret_cast<bf16x8*>(afw + (s + d) * 512) = o;
      }
      // counted-wait barrier: drain LDS only; global loads stay in flight
      asm volatile("s_waitcnt lgkmcnt(0)" ::: "memory");
      __builtin_amdgcn_s_barrier();
    }
  }
  __syncthreads();   // Af fully populated (needed below by ctx phase)

  // ---- scores epilogue: tanh(acc + hw[u]) * Va[u], reduce over u ----
  const float* hwb = hw + b * UU;
  float part[8][4];
#pragma unroll
  for (int mf = 0; mf < 8; ++mf)
#pragma unroll
    for (int r = 0; r < 4; ++r) part[mf][r] = 0.f;
#pragma unroll
  for (int nf = 0; nf < 4; ++nf) {
    const int u = w * 64 + nf * 16 + lo;
    const float hv = hwb[u];
    const float vv = Va[u];
#pragma unroll
    for (int mf = 0; mf < 8; ++mf)
#pragma unroll
      for (int r = 0; r < 4; ++r)
        part[mf][r] += tanh_fast(acc[mf][nf][r] + hv) * vv;
  }
#pragma unroll
  for (int mf = 0; mf < 8; ++mf)
#pragma unroll
    for (int r = 0; r < 4; ++r) {
      float s = part[mf][r];
      s += __shfl_xor(s, 1);
      s += __shfl_xor(s, 2);
      s += __shfl_xor(s, 4);
      s += __shfl_xor(s, 8);
      part[mf][r] = s;
    }
  if (lo == 0) {
#pragma unroll
    for (int mf = 0; mf < 8; ++mf)
#pragma unroll
      for (int r = 0; r < 4; ++r)
        red[w][mf * 16 + g * 4 + r] = part[mf][r];
  }
  __syncthreads();

  // ---- tile softmax stats over 128 rows (2 waves) ----
  if (tid < 128) {
    float s = red[0][tid] + red[1][tid] + red[2][tid] + red[3][tid] +
              red[4][tid] + red[5][tid] + red[6][tid] + red[7][tid];
    sred[tid] = s;
    float m = s;
#pragma unroll
    for (int off = 1; off < 64; off <<= 1) m = fmaxf(m, __shfl_xor(m, off));
    if ((tid & 63) == 0) wtmp[tid >> 6] = m;
  }
  __syncthreads();
  if (tid < 128) {
    float m = fmaxf(wtmp[0], wtmp[1]);
    float e = __expf(sred[tid] - m);
    e_all[tid] = e;
    float ls = e;
#pragma unroll
    for (int off = 1; off < 64; off <<= 1) ls += __shfl_xor(ls, off);
    if ((tid & 63) == 0) wtmp[2 + (tid >> 6)] = ls;
    if (tid == 0) mbuf[b * 16 + tile] = m;
  }
  __syncthreads();
  if (tid == 0) lbuf[b * 16 + tile] = wtmp[2] + wtmp[3];

  // ---- partial context, vectorized: 64 f-owners x 8 t-slices ----
  {
    const int fo = tid & 63;         // kk2 = fo>>2, gg = fo&3
    const int ts = tid >> 6;         // t-slice: t in [ts*16, ts*16+16)
    const int kk2 = fo >> 2;
    const int gg = fo & 3;
    float a8[8];
#pragma unroll
    for (int j = 0; j < 8; ++j) a8[j] = 0.f;
#pragma unroll
    for (int it = 0; it < 16; ++it) {
      const int tl = (it + fo) & 15;           // stagger vs bank collisions
      const int t = ts * 16 + tl;
      const int entry = (ts * 16 + kk2) * 64 + gg * 16 + tl;
      bf16x8 v = *reinterpret_cast<const bf16x8*>(&Af[entry * 8]);
      const float e = e_all[t];
#pragma unroll
      for (int j = 0; j < 8; ++j)
        a8[j] += e * bf2f((unsigned short)v[j]);
    }
#pragma unroll
    for (int j = 0; j < 8; ++j) ctxp[ts][fo * 8 + j] = a8[j];
  }
  __syncthreads();
  {
    float s = 0.f;
#pragma unroll
    for (int ts2 = 0; ts2 < 8; ++ts2) s += ctxp[ts2][tid];
    const int fo2 = tid >> 3;
    const int j2 = tid & 7;
    const int f = (fo2 >> 2) * 32 +
                  ((j2 < 4) ? (fo2 & 3) * 4 + j2 : 16 + (fo2 & 3) * 4 + (j2 - 4));
    cpart[(size_t)(b * 16 + tile) * 512 + f] = s;
  }
}

// Combine tile partials: c is consumed inside k5a; this kernel remains for
// clarity of the math in k5a's fused combine. (not launched)

// --- gate GEMMs, LDS-tiled, split-K x8, NON-ATOMIC partials ---------------
__global__ __launch_bounds__(512) void k5a_gates(
    const float* __restrict__ x, const float* __restrict__ mbuf,
    const float* __restrict__ lbuf, const float* __restrict__ cpart,
    const float* __restrict__ h, const float* __restrict__ kern,
    const float* __restrict__ ak, const float* __restrict__ rk,
    float* __restrict__ Gp) {
  __shared__ float wsx[64][64], wsa[64][64], wsr[64][64];
  __shared__ float xs[32][64], cs[32][64], hs[32][64];
  __shared__ float lsm[512], lsl[512], lwinv[512];
  const int n0 = blockIdx.x * 64;
  const int kg = blockIdx.y;
  const int kg0 = kg * 64;
  const bool has_r = (n0 < 1024);
  const int tid = threadIdx.x;
  const int n = tid & 63;
  const int b0 = (tid >> 6) * 4;
  const int wrow = tid >> 3, wcol = (tid & 7) * 8;
  const int orow = tid >> 4, ocol = (tid & 15) * 4;
  float acc[4] = {0.f, 0.f, 0.f, 0.f};

  lsm[tid] = mbuf[tid];
  lsl[tid] = lbuf[tid];

  {
    const size_t wb = (size_t)(kg0 + wrow) * 1536 + n0 + wcol;
    *reinterpret_cast<float4*>(&wsx[wrow][wcol])     = *reinterpret_cast<const float4*>(kern + wb);
    *reinterpret_cast<float4*>(&wsx[wrow][wcol + 4]) = *reinterpret_cast<const float4*>(kern + wb + 4);
    *reinterpret_cast<float4*>(&wsa[wrow][wcol])     = *reinterpret_cast<const float4*>(ak + wb);
    *reinterpret_cast<float4*>(&wsa[wrow][wcol + 4]) = *reinterpret_cast<const float4*>(ak + wb + 4);
    if (has_r) {
      *reinterpret_cast<float4*>(&wsr[wrow][wcol])     = *reinterpret_cast<const float4*>(rk + wb);
      *reinterpret_cast<float4*>(&wsr[wrow][wcol + 4]) = *reinterpret_cast<const float4*>(rk + wb + 4);
    }
    *reinterpret_cast<float4*>(&xs[orow][ocol]) =
        *reinterpret_cast<const float4*>(x + orow * FF + kg0 + ocol);
    *reinterpret_cast<float4*>(&hs[orow][ocol]) =
        *reinterpret_cast<const float4*>(h + orow * UU + kg0 + ocol);
  }
  __syncthreads();

  // winv[b][i] = exp(m_i - M_b) / D_b
  if (tid < 32) {
    float M = -1e30f;
#pragma unroll
    for (int i = 0; i < 16; ++i) M = fmaxf(M, lsm[tid * 16 + i]);
    float D = 0.f;
#pragma unroll
    for (int i = 0; i < 16; ++i)
      D += __expf(lsm[tid * 16 + i] - M) * lsl[tid * 16 + i];
    const float inv = 1.f / D;
#pragma unroll
    for (int i = 0; i < 16; ++i)
      lwinv[tid * 16 + i] = __expf(lsm[tid * 16 + i] - M) * inv;
  }
  __syncthreads();

  // cs[orow][ocol..+3] = c[orow][kg0+ocol..+3] from cpart
  {
    float4 cv = {0.f, 0.f, 0.f, 0.f};
#pragma unroll
    for (int i = 0; i < 16; ++i) {
      const float wi = lwinv[orow * 16 + i];
      const float4 cp = *reinterpret_cast<const float4*>(
          &cpart[(size_t)(orow * 16 + i) * 512 + kg0 + ocol]);
      cv.x += wi * cp.x; cv.y += wi * cp.y;
      cv.z += wi * cp.z; cv.w += wi * cp.w;
    }
    *reinterpret_cast<float4*>(&cs[orow][ocol]) = cv;
  }
  __syncthreads();

  if (has_r) {
#pragma unroll 8
    for (int k = 0; k < 64; ++k) {
      const float wx = wsx[k][n], wa = wsa[k][n], wr = wsr[k][n];
#pragma unroll
      for (int j = 0; j < 4; ++j)
        acc[j] += xs[b0 + j][k] * wx + cs[b0 + j][k] * wa + hs[b0 + j][k] * wr;
    }
  } else {
#pragma unroll 8
    for (int k = 0; k < 64; ++k) {
      const float wx = wsx[k][n], wa = wsa[k][n];
#pragma unroll
      for (int j = 0; j < 4; ++j)
        acc[j] += xs[b0 + j][k] * wx + cs[b0 + j][k] * wa;
    }
  }
#pragma unroll
  for (int j = 0; j < 4; ++j)
    Gp[(size_t)kg * 49152 + (size_t)(b0 + j) * 1536 + n0 + n] = acc[j];
}

// k5c with fused r-gate: rs computed inline from Gp sums.
__global__ __launch_bounds__(512) void k5c_q(
    const float* __restrict__ Gp, const float* __restrict__ h,
    const float* __restrict__ bias, const float* __restrict__ abias,
    const float* __restrict__ rk, float* __restrict__ qp) {
  __shared__ float wsr[64][64];
  __shared__ float rs[32][64];
  const int n0 = blockIdx.x * 64;
  const int kg = blockIdx.y;
  const int kg0 = kg * 64;
  const int tid = threadIdx.x;
  const int n = tid & 63;
  const int b0 = (tid >> 6) * 4;
  const int wrow = tid >> 3, wcol = (tid & 7) * 8;
  const int orow = tid >> 4, ocol = (tid & 15) * 4;
  float acc[4] = {0.f, 0.f, 0.f, 0.f};

  {
    const size_t wb = (size_t)(kg0 + wrow) * 1536 + 1024 + n0 + wcol;
    *reinterpret_cast<float4*>(&wsr[wrow][wcol])     = *reinterpret_cast<const float4*>(rk + wb);
    *reinterpret_cast<float4*>(&wsr[wrow][wcol + 4]) = *reinterpret_cast<const float4*>(rk + wb + 4);
  }
  {
    const int u = kg0 + ocol;
    float4 sr = *reinterpret_cast<const float4*>(bias + 512 + u);
    const float4 ab = *reinterpret_cast<const float4*>(abias + 512 + u);
    sr.x += ab.x; sr.y += ab.y; sr.z += ab.z; sr.w += ab.w;
#pragma unroll
    for (int p = 0; p < 8; ++p) {
      const float4 gp4 = *reinterpret_cast<const float4*>(
          Gp + (size_t)p * 49152 + (size_t)orow * 1536 + 512 + u);
      sr.x += gp4.x; sr.y += gp4.y; sr.z += gp4.z; sr.w += gp4.w;
    }
    const float4 hv = *reinterpret_cast<const float4*>(h + orow * UU + u);
    rs[orow][ocol]     = fminf(fmaxf(0.2f * sr.x + 0.5f, 0.f), 1.f) * hv.x;
    rs[orow][ocol + 1] = fminf(fmaxf(0.2f * sr.y + 0.5f, 0.f), 1.f) * hv.y;
    rs[orow][ocol + 2] = fminf(fmaxf(0.2f * sr.z + 0.5f, 0.f), 1.f) * hv.z;
    rs[orow][ocol + 3] = fminf(fmaxf(0.2f * sr.w + 0.5f, 0.f), 1.f) * hv.w;
  }
  __syncthreads();
#pragma unroll 8
  for (int k = 0; k < 64; ++k) {
    const float w = wsr[k][n];
#pragma unroll
    for (int j = 0; j < 4; ++j) acc[j] += rs[b0 + j][k] * w;
  }
#pragma unroll
  for (int j = 0; j < 4; ++j)
    qp[(size_t)kg * 16384 + (b0 + j) * UU + n0 + n] = acc[j];
}

// k5d: z and hh from summed partials.
__global__ __launch_bounds__(256) void k5d_out(
    const float* __restrict__ Gp, const float* __restrict__ qp,
    const float* __restrict__ h, const float* __restrict__ bias,
    const float* __restrict__ abias, float* __restrict__ out) {
  int idx = blockIdx.x * blockDim.x + threadIdx.x;  // 16384
  int b = idx >> 9;
  int u = idx & 511;
  float sz = bias[u] + abias[u];
  float sh = bias[1024 + u] + abias[1024 + u];
  const float* gb = Gp + (size_t)b * 1536;
  const float* qb = qp + (size_t)b * 512;
#pragma unroll
  for (int p = 0; p < 8; ++p) {
    sz += gb[(size_t)p * 49152 + u];
    sh += gb[(size_t)p * 49152 + 1024 + u] + qb[(size_t)p * 16384 + u];
  }
  float z = fminf(fmaxf(0.2f * sz + 0.5f, 0.f), 1.f);
  float hh = tanhf(sh);
  out[idx] = z * h[idx] + (1.f - z) * hh;
}

extern "C" void kernel_launch(void* const* d_in, const int* in_sizes, int n_in,
                              void* d_out, int out_size, void* d_ws, size_t ws_size,
                              hipStream_t stream) {
  const float* x       = (const float*)d_in[0];
  const float* h       = (const float*)d_in[1];
  const float* ann     = (const float*)d_in[2];
  const float* kern    = (const float*)d_in[3];
  const float* rk      = (const float*)d_in[4];
  const float* ak      = (const float*)d_in[5];
  const float* Wa      = (const float*)d_in[6];
  const float* Ua      = (const float*)d_in[7];
  const float* Va      = (const float*)d_in[8];
  const float* bias    = (const float*)d_in[9];
  const float* abias   = (const float*)d_in[10];
  const float* Wa_bias = (const float*)d_in[11];
  const float* Ua_bias = (const float*)d_in[12];

  float* ws     = (float*)d_ws;
  float* hw     = ws;            // 16384
  float* mbuf   = ws + 16384;    // 512
  float* lbuf   = ws + 16896;    // 512
  float* cpart  = ws + 17408;    // 262144
  float* Gp     = ws + 279552;   // 393216 (8 x 32 x 1536)
  float* qp     = ws + 672768;   // 131072 (8 x 32 x 512)
  short* Up     = (short*)(ws + 803840);  // 262144 shorts

  dim3 g0(32, 16);
  k0_pack<<<g0, 64, 0, stream>>>(Ua, Up);

  k1_hw<<<64, 256, 0, stream>>>(h, Wa, Wa_bias, Ua_bias, hw);

  dim3 g2(TT / 128, BB);
  k2_flash<<<g2, 512, 0, stream>>>(ann, Up, Va, hw, mbuf, lbuf, cpart);

  dim3 g5a(24, 8);
  k5a_gates<<<g5a, 512, 0, stream>>>(x, mbuf, lbuf, cpart, h, kern, ak, rk, Gp);

  dim3 g5c(8, 8);
  k5c_q<<<g5c, 512, 0, stream>>>(Gp, h, bias, abias, rk, qp);

  k5d_out<<<64, 256, 0, stream>>>(Gp, qp, h, bias, abias, (float*)d_out);
}

// Round 17
// 94.272 us; speedup vs baseline: 1.1621x; 1.0966x over previous
//
#include <hip/hip_runtime.h>
#include <hip/hip_bf16.h>
#include <math.h>

#define BB 32
#define TT 2048
#define FF 512
#define UU 512

typedef __attribute__((ext_vector_type(4))) float f32x4;
typedef __attribute__((ext_vector_type(4))) short bf16x4;
typedef __attribute__((ext_vector_type(8))) short bf16x8;

__device__ inline short f2bf(float f) {
  union { __hip_bfloat16 h; short s; } u;
  u.h = __float2bfloat16(f);
  return u.s;
}

__device__ inline float bf2f(unsigned short s) {
  return __uint_as_float(((unsigned)s) << 16);
}

// tanh(x) = 1 - 2/(exp(2x)+1). ~6 VALU ops, ~1e-6 abs err, saturates right.
__device__ inline float tanh_fast(float x) {
  float e = __expf(2.0f * x);
  return 1.0f - 2.0f * __builtin_amdgcn_rcpf(e + 1.0f);
}

// ws layout (floats) -- no memset needed; every buffer fully written:
// hw:     [0,      16384)
// mbuf:   [16384,  16896)    32 b x 16 tiles
// lbuf:   [16896,  17408)
// cpart:  [17408,  279552)   32 b x 16 tiles x 512 f (f32)
// c:      [279552, 295936)
// Gp:     [295936, 689152)   8 ksl x 32 b x 1536 n  (non-atomic partials)
// qp:     [689152, 820224)   8 ksl x 32 b x 512 u
// zs:     [820224, 836608)
// rh:     [836608, 852992)
// Up:     shorts at float-offset 852992 (262144 shorts = 512 KB)

__global__ __launch_bounds__(256) void k1_hw(
    const float* __restrict__ h, const float* __restrict__ Wa,
    const float* __restrict__ Wa_bias, const float* __restrict__ Ua_bias,
    float* __restrict__ hw) {
  int idx = blockIdx.x * blockDim.x + threadIdx.x;  // 16384 = B*U
  int b = idx >> 9;
  int u = idx & 511;
  float acc = Wa_bias[u] + Ua_bias[u];
  const float* hrow = h + b * UU;
  for (int f = 0; f < FF; ++f) acc += hrow[f] * Wa[f * UU + u];
  hw[idx] = acc;
}

// Pack Ua (fp32 [k][n]) into fragment-native bf16 layout.
__global__ __launch_bounds__(64) void k0_pack(
    const float* __restrict__ Ua, short* __restrict__ Up) {
  const int n16 = blockIdx.x;   // 0..31
  const int k32 = blockIdx.y;   // 0..15
  const int l = threadIdx.x;    // 0..63
  const int n = n16 * 16 + (l & 15);
  const int g = l >> 4;
  bf16x8 v;
#pragma unroll
  for (int i = 0; i < 8; ++i) {
    int k = k32 * 32 + (i < 4 ? g * 4 + i : 16 + g * 4 + (i - 4));
    v[i] = f2bf(Ua[k * UU + n]);
  }
  *reinterpret_cast<bf16x8*>(Up + ((size_t)(n16 * 16 + k32) * 64 + l) * 8) = v;
}

// Flash kernel v9 (champion): chunk-pipelined stage with counted-wait
// barriers -- the in-loop __syncthreads() (which drains vmcnt to 0) is
// replaced by lgkmcnt(0) + raw s_barrier, so the chunk s+2 global loads and
// B refills stay in flight across the barrier. t-tile=128, 512 thr, 1 blk/CU.
__global__ __launch_bounds__(512, 2) void k2_flash(
    const float* __restrict__ ann, const short* __restrict__ Up,
    const float* __restrict__ Va, const float* __restrict__ hw,
    float* __restrict__ mbuf, float* __restrict__ lbuf,
    float* __restrict__ cpart) {
  __shared__ short Af[65536];      // 128 fb x 64 lane x 8 bf16 = 128 KB
  __shared__ float red[8][128];    // 4 KB
  __shared__ float e_all[128];
  __shared__ float sred[128];
  __shared__ float wtmp[4];
  __shared__ float ctxp[8][512];   // 16 KB
  const int tile = blockIdx.x;     // 0..15
  const int b = blockIdx.y;
  const int t0 = tile * 128;
  const int tid = threadIdx.x;     // 0..511
  const int w = tid >> 6;          // wave 0..7
  const int l = tid & 63;
  const int lo = l & 15;
  const int g = l >> 4;

  const float* annb = ann + ((size_t)b * TT + t0) * FF;
  // this thread's staging source row (fixed): wave w stages rows w*16+lo
  const float* srow = annb + (size_t)(w * 16 + lo) * FF + g * 4;
  // this thread's staging LDS entry base for chunk s: E = (w*16+s)*64 + l
  short* const afw = &Af[((w * 16) * 64 + l) * 8];

  const short* upb[4];
  upb[0] = Up + ((size_t)((w * 4 + 0) * 16) * 64 + l) * 8;
  upb[1] = Up + ((size_t)((w * 4 + 1) * 16) * 64 + l) * 8;
  upb[2] = Up + ((size_t)((w * 4 + 2) * 16) * 64 + l) * 8;
  upb[3] = Up + ((size_t)((w * 4 + 3) * 16) * 64 + l) * 8;

  f32x4 acc[8][4];
#pragma unroll
  for (int mf = 0; mf < 8; ++mf)
#pragma unroll
    for (int nf = 0; nf < 4; ++nf) acc[mf][nf] = (f32x4)0.f;

  // chunk staging registers, parity-indexed (constant indices after unroll)
  f32x4 stg[2][2];
  bf16x8 bb[2][4];

  // ---- prologue: load chunks 0,1; write chunk 0; load B slots 0,1 ----
  stg[0][0] = *reinterpret_cast<const f32x4*>(srow + 0 * 32);
  stg[0][1] = *reinterpret_cast<const f32x4*>(srow + 0 * 32 + 16);
  stg[1][0] = *reinterpret_cast<const f32x4*>(srow + 1 * 32);
  stg[1][1] = *reinterpret_cast<const f32x4*>(srow + 1 * 32 + 16);
#pragma unroll
  for (int nf = 0; nf < 4; ++nf) {
    bb[0][nf] = *reinterpret_cast<const bf16x8*>(upb[nf]);
    bb[1][nf] = *reinterpret_cast<const bf16x8*>(upb[nf] + 512);
  }
  {
    bf16x8 o;
    o[0] = f2bf(stg[0][0].x); o[1] = f2bf(stg[0][0].y);
    o[2] = f2bf(stg[0][0].z); o[3] = f2bf(stg[0][0].w);
    o[4] = f2bf(stg[0][1].x); o[5] = f2bf(stg[0][1].y);
    o[6] = f2bf(stg[0][1].z); o[7] = f2bf(stg[0][1].w);
    *reinterpret_cast<bf16x8*>(afw + 0 * 512) = o;
  }
  __syncthreads();

  // ---- pipelined main loop over k-slots ----
#pragma unroll
  for (int s = 0; s < 16; ++s) {
    // issue chunk s+2 global loads into stg[s&1] (chunk s already in LDS)
    if (s < 14) {
      stg[s & 1][0] = *reinterpret_cast<const f32x4*>(srow + (s + 2) * 32);
      stg[s & 1][1] = *reinterpret_cast<const f32x4*>(srow + (s + 2) * 32 + 16);
    }
    // A fragments for slot s
    bf16x8 aA[8];
#pragma unroll
    for (int mf = 0; mf < 8; ++mf)
      aA[mf] = *reinterpret_cast<const bf16x8*>(
          &Af[((mf * 16 + s) * 64 + l) * 8]);
    __builtin_amdgcn_s_setprio(1);
#pragma unroll
    for (int mf = 0; mf < 8; ++mf)
#pragma unroll
      for (int nf = 0; nf < 4; ++nf)
        acc[mf][nf] = __builtin_amdgcn_mfma_f32_16x16x32_bf16(
            aA[mf], bb[s & 1][nf], acc[mf][nf], 0, 0, 0);
    __builtin_amdgcn_s_setprio(0);
    // refill B slot s+2 into bb[s&1] (just consumed)
    if (s < 14) {
#pragma unroll
      for (int nf = 0; nf < 4; ++nf)
        bb[s & 1][nf] =
            *reinterpret_cast<const bf16x8*>(upb[nf] + (s + 2) * 512);
    }
    // cvt + write chunk s+1 (loads issued at iter s-1, covered by MFMA)
    if (s < 15) {
      const f32x4 c0 = stg[(s + 1) & 1][0];
      const f32x4 c1 = stg[(s + 1) & 1][1];
      bf16x8 o;
      o[0] = f2bf(c0.x); o[1] = f2bf(c0.y); o[2] = f2bf(c0.z); o[3] = f2bf(c0.w);
      o[4] = f2bf(c1.x); o[5] = f2bf(c1.y); o[6] = f2bf(c1.z); o[7] = f2bf(c1.w);
      *reinterpret_cast<bf16x8*>(afw + (s + 1) * 512) = o;
      // counted-wait barrier: drain LDS ops only; global loads stay in flight
      asm volatile("s_waitcnt lgkmcnt(0)" ::: "memory");
      __builtin_amdgcn_s_barrier();
    }
  }
  __syncthreads();   // Af fully populated (needed below by ctx phase)

  // ---- scores epilogue: tanh(acc + hw[u]) * Va[u], reduce over u ----
  const float* hwb = hw + b * UU;
  float part[8][4];
#pragma unroll
  for (int mf = 0; mf < 8; ++mf)
#pragma unroll
    for (int r = 0; r < 4; ++r) part[mf][r] = 0.f;
#pragma unroll
  for (int nf = 0; nf < 4; ++nf) {
    const int u = w * 64 + nf * 16 + lo;
    const float hv = hwb[u];
    const float vv = Va[u];
#pragma unroll
    for (int mf = 0; mf < 8; ++mf)
#pragma unroll
      for (int r = 0; r < 4; ++r)
        part[mf][r] += tanh_fast(acc[mf][nf][r] + hv) * vv;
  }
#pragma unroll
  for (int mf = 0; mf < 8; ++mf)
#pragma unroll
    for (int r = 0; r < 4; ++r) {
      float s = part[mf][r];
      s += __shfl_xor(s, 1);
      s += __shfl_xor(s, 2);
      s += __shfl_xor(s, 4);
      s += __shfl_xor(s, 8);
      part[mf][r] = s;
    }
  if (lo == 0) {
#pragma unroll
    for (int mf = 0; mf < 8; ++mf)
#pragma unroll
      for (int r = 0; r < 4; ++r)
        red[w][mf * 16 + g * 4 + r] = part[mf][r];
  }
  __syncthreads();

  // ---- tile softmax stats over 128 rows (2 waves) ----
  if (tid < 128) {
    float s = red[0][tid] + red[1][tid] + red[2][tid] + red[3][tid] +
              red[4][tid] + red[5][tid] + red[6][tid] + red[7][tid];
    sred[tid] = s;
    float m = s;
#pragma unroll
    for (int off = 1; off < 64; off <<= 1) m = fmaxf(m, __shfl_xor(m, off));
    if ((tid & 63) == 0) wtmp[tid >> 6] = m;
  }
  __syncthreads();
  if (tid < 128) {
    float m = fmaxf(wtmp[0], wtmp[1]);
    float e = __expf(sred[tid] - m);
    e_all[tid] = e;
    float ls = e;
#pragma unroll
    for (int off = 1; off < 64; off <<= 1) ls += __shfl_xor(ls, off);
    if ((tid & 63) == 0) wtmp[2 + (tid >> 6)] = ls;
    if (tid == 0) mbuf[b * 16 + tile] = m;
  }
  __syncthreads();
  if (tid == 0) lbuf[b * 16 + tile] = wtmp[2] + wtmp[3];

  // ---- partial context, vectorized: 64 f-owners x 8 t-slices ----
  {
    const int fo = tid & 63;         // kk2 = fo>>2, gg = fo&3
    const int ts = tid >> 6;         // t-slice: t in [ts*16, ts*16+16)
    const int kk2 = fo >> 2;
    const int gg = fo & 3;
    float a8[8];
#pragma unroll
    for (int j = 0; j < 8; ++j) a8[j] = 0.f;
#pragma unroll
    for (int it = 0; it < 16; ++it) {
      const int tl = (it + fo) & 15;           // stagger vs bank collisions
      const int t = ts * 16 + tl;
      const int entry = (ts * 16 + kk2) * 64 + gg * 16 + tl;
      bf16x8 v = *reinterpret_cast<const bf16x8*>(&Af[entry * 8]);
      const float e = e_all[t];
#pragma unroll
      for (int j = 0; j < 8; ++j)
        a8[j] += e * bf2f((unsigned short)v[j]);
    }
#pragma unroll
    for (int j = 0; j < 8; ++j) ctxp[ts][fo * 8 + j] = a8[j];
  }
  __syncthreads();
  {
    float s = 0.f;
#pragma unroll
    for (int ts2 = 0; ts2 < 8; ++ts2) s += ctxp[ts2][tid];
    const int fo2 = tid >> 3;
    const int j2 = tid & 7;
    const int f = (fo2 >> 2) * 32 +
                  ((j2 < 4) ? (fo2 & 3) * 4 + j2 : 16 + (fo2 & 3) * 4 + (j2 - 4));
    cpart[(size_t)(b * 16 + tile) * 512 + f] = s;
  }
}

// Combine tile partials: c[b][f] = sum_i w_i*cpart_i[f] / sum_i w_i*l_i.
__global__ __launch_bounds__(256) void k6_combine(
    const float* __restrict__ mbuf, const float* __restrict__ lbuf,
    const float* __restrict__ cpart, float* __restrict__ c) {
  const int b = blockIdx.x;
  const int tid = threadIdx.x;
  __shared__ float sm[16], sl[16];
  if (tid < 16) {
    sm[tid] = mbuf[b * 16 + tid];
    sl[tid] = lbuf[b * 16 + tid];
  }
  __syncthreads();
  float M = -1e30f;
#pragma unroll
  for (int i = 0; i < 16; ++i) M = fmaxf(M, sm[i]);
  float D = 0.f;
#pragma unroll
  for (int i = 0; i < 16; ++i) D += __expf(sm[i] - M) * sl[i];
  const float inv = 1.f / D;
  const int f = tid * 2;
  float a0 = 0.f, a1 = 0.f;
#pragma unroll
  for (int i = 0; i < 16; ++i) {
    const float wi = __expf(sm[i] - M);
    const float2 v = *reinterpret_cast<const float2*>(
        &cpart[(size_t)(b * 16 + i) * 512 + f]);
    a0 += wi * v.x;
    a1 += wi * v.y;
  }
  c[b * FF + f]     = a0 * inv;
  c[b * FF + f + 1] = a1 * inv;
}

// --- gate GEMMs, LDS-tiled, split-K x8, NON-ATOMIC partials ---------------
// Gp[kg][b][n] = partial over k in [kg*64, kg*64+64).
__global__ __launch_bounds__(512) void k5a_gates(
    const float* __restrict__ x, const float* __restrict__ cc,
    const float* __restrict__ h, const float* __restrict__ kern,
    const float* __restrict__ ak, const float* __restrict__ rk,
    float* __restrict__ Gp) {
  __shared__ float wsx[64][64], wsa[64][64], wsr[64][64];
  __shared__ float xs[32][64], cs[32][64], hs[32][64];
  const int n0 = blockIdx.x * 64;
  const int kg = blockIdx.y;
  const int kg0 = kg * 64;
  const bool has_r = (n0 < 1024);
  const int tid = threadIdx.x;
  const int n = tid & 63;
  const int b0 = (tid >> 6) * 4;
  const int wrow = tid >> 3, wcol = (tid & 7) * 8;
  const int orow = tid >> 4, ocol = (tid & 15) * 4;
  float acc[4] = {0.f, 0.f, 0.f, 0.f};

  {
    const size_t wb = (size_t)(kg0 + wrow) * 1536 + n0 + wcol;
    *reinterpret_cast<float4*>(&wsx[wrow][wcol])     = *reinterpret_cast<const float4*>(kern + wb);
    *reinterpret_cast<float4*>(&wsx[wrow][wcol + 4]) = *reinterpret_cast<const float4*>(kern + wb + 4);
    *reinterpret_cast<float4*>(&wsa[wrow][wcol])     = *reinterpret_cast<const float4*>(ak + wb);
    *reinterpret_cast<float4*>(&wsa[wrow][wcol + 4]) = *reinterpret_cast<const float4*>(ak + wb + 4);
    if (has_r) {
      *reinterpret_cast<float4*>(&wsr[wrow][wcol])     = *reinterpret_cast<const float4*>(rk + wb);
      *reinterpret_cast<float4*>(&wsr[wrow][wcol + 4]) = *reinterpret_cast<const float4*>(rk + wb + 4);
    }
    *reinterpret_cast<float4*>(&xs[orow][ocol]) =
        *reinterpret_cast<const float4*>(x + orow * FF + kg0 + ocol);
    *reinterpret_cast<float4*>(&cs[orow][ocol]) =
        *reinterpret_cast<const float4*>(cc + orow * FF + kg0 + ocol);
    *reinterpret_cast<float4*>(&hs[orow][ocol]) =
        *reinterpret_cast<const float4*>(h + orow * UU + kg0 + ocol);
  }
  __syncthreads();
  if (has_r) {
#pragma unroll 8
    for (int k = 0; k < 64; ++k) {
      const float wx = wsx[k][n], wa = wsa[k][n], wr = wsr[k][n];
#pragma unroll
      for (int j = 0; j < 4; ++j)
        acc[j] += xs[b0 + j][k] * wx + cs[b0 + j][k] * wa + hs[b0 + j][k] * wr;
    }
  } else {
#pragma unroll 8
    for (int k = 0; k < 64; ++k) {
      const float wx = wsx[k][n], wa = wsa[k][n];
#pragma unroll
      for (int j = 0; j < 4; ++j)
        acc[j] += xs[b0 + j][k] * wx + cs[b0 + j][k] * wa;
    }
  }
#pragma unroll
  for (int j = 0; j < 4; ++j)
    Gp[(size_t)kg * 49152 + (size_t)(b0 + j) * 1536 + n0 + n] = acc[j];
}

// k5b: z, r from summed partials; rh = r*h, zs = z.
__global__ __launch_bounds__(256) void k5b_zr(
    const float* __restrict__ Gp, const float* __restrict__ h,
    const float* __restrict__ bias, const float* __restrict__ abias,
    float* __restrict__ zs, float* __restrict__ rh) {
  int idx = blockIdx.x * blockDim.x + threadIdx.x;  // 16384
  int b = idx >> 9;
  int u = idx & 511;
  float sz = bias[u] + abias[u];
  float sr = bias[512 + u] + abias[512 + u];
  const float* gb = Gp + (size_t)b * 1536;
#pragma unroll
  for (int p = 0; p < 8; ++p) {
    sz += gb[(size_t)p * 49152 + u];
    sr += gb[(size_t)p * 49152 + 512 + u];
  }
  float z = fminf(fmaxf(0.2f * sz + 0.5f, 0.f), 1.f);
  float r = fminf(fmaxf(0.2f * sr + 0.5f, 0.f), 1.f);
  zs[idx] = z;
  rh[idx] = r * h[idx];
}

// k5c: qp[kg][b][u] partial of rh @ rk_h, non-atomic.
__global__ __launch_bounds__(512) void k5c_q(
    const float* __restrict__ rh, const float* __restrict__ rk,
    float* __restrict__ qp) {
  __shared__ float wsr[64][64];
  __shared__ float rs[32][64];
  const int n0 = blockIdx.x * 64;
  const int kg = blockIdx.y;
  const int kg0 = kg * 64;
  const int tid = threadIdx.x;
  const int n = tid & 63;
  const int b0 = (tid >> 6) * 4;
  const int wrow = tid >> 3, wcol = (tid & 7) * 8;
  const int orow = tid >> 4, ocol = (tid & 15) * 4;
  float acc[4] = {0.f, 0.f, 0.f, 0.f};

  {
    const size_t wb = (size_t)(kg0 + wrow) * 1536 + 1024 + n0 + wcol;
    *reinterpret_cast<float4*>(&wsr[wrow][wcol])     = *reinterpret_cast<const float4*>(rk + wb);
    *reinterpret_cast<float4*>(&wsr[wrow][wcol + 4]) = *reinterpret_cast<const float4*>(rk + wb + 4);
    *reinterpret_cast<float4*>(&rs[orow][ocol]) =
        *reinterpret_cast<const float4*>(rh + orow * UU + kg0 + ocol);
  }
  __syncthreads();
#pragma unroll 8
  for (int k = 0; k < 64; ++k) {
    const float w = wsr[k][n];
#pragma unroll
    for (int j = 0; j < 4; ++j) acc[j] += rs[b0 + j][k] * w;
  }
#pragma unroll
  for (int j = 0; j < 4; ++j)
    qp[(size_t)kg * 16384 + (b0 + j) * UU + n0 + n] = acc[j];
}

// k5d: hh from summed partials; out = zs*h + (1-zs)*hh.
__global__ __launch_bounds__(256) void k5d_out(
    const float* __restrict__ Gp, const float* __restrict__ qp,
    const float* __restrict__ zs, const float* __restrict__ h,
    const float* __restrict__ bias, const float* __restrict__ abias,
    float* __restrict__ out) {
  int idx = blockIdx.x * blockDim.x + threadIdx.x;  // 16384
  int b = idx >> 9;
  int u = idx & 511;
  float sh = bias[1024 + u] + abias[1024 + u];
  const float* gb = Gp + (size_t)b * 1536;
  const float* qb = qp + (size_t)b * 512;
#pragma unroll
  for (int p = 0; p < 8; ++p) {
    sh += gb[(size_t)p * 49152 + 1024 + u];
    sh += qb[(size_t)p * 16384 + u];
  }
  float hh = tanhf(sh);
  float z = zs[idx];
  out[idx] = z * h[idx] + (1.f - z) * hh;
}

extern "C" void kernel_launch(void* const* d_in, const int* in_sizes, int n_in,
                              void* d_out, int out_size, void* d_ws, size_t ws_size,
                              hipStream_t stream) {
  const float* x       = (const float*)d_in[0];
  const float* h       = (const float*)d_in[1];
  const float* ann     = (const float*)d_in[2];
  const float* kern    = (const float*)d_in[3];
  const float* rk      = (const float*)d_in[4];
  const float* ak      = (const float*)d_in[5];
  const float* Wa      = (const float*)d_in[6];
  const float* Ua      = (const float*)d_in[7];
  const float* Va      = (const float*)d_in[8];
  const float* bias    = (const float*)d_in[9];
  const float* abias   = (const float*)d_in[10];
  const float* Wa_bias = (const float*)d_in[11];
  const float* Ua_bias = (const float*)d_in[12];

  float* ws     = (float*)d_ws;
  float* hw     = ws;            // 16384
  float* mbuf   = ws + 16384;    // 512
  float* lbuf   = ws + 16896;    // 512
  float* cpart  = ws + 17408;    // 262144
  float* c      = ws + 279552;   // 16384
  float* Gp     = ws + 295936;   // 393216 (8 x 32 x 1536)
  float* qp     = ws + 689152;   // 131072 (8 x 32 x 512)
  float* zs     = ws + 820224;   // 16384
  float* rh     = ws + 836608;   // 16384
  short* Up     = (short*)(ws + 852992);  // 262144 shorts

  dim3 g0(32, 16);
  k0_pack<<<g0, 64, 0, stream>>>(Ua, Up);

  k1_hw<<<64, 256, 0, stream>>>(h, Wa, Wa_bias, Ua_bias, hw);

  dim3 g2(TT / 128, BB);
  k2_flash<<<g2, 512, 0, stream>>>(ann, Up, Va, hw, mbuf, lbuf, cpart);

  k6_combine<<<BB, 256, 0, stream>>>(mbuf, lbuf, cpart, c);

  dim3 g5a(24, 8);
  k5a_gates<<<g5a, 512, 0, stream>>>(x, c, h, kern, ak, rk, Gp);

  k5b_zr<<<64, 256, 0, stream>>>(Gp, h, bias, abias, zs, rh);

  dim3 g5c(8, 8);
  k5c_q<<<g5c, 512, 0, stream>>>(rh, rk, qp);

  k5d_out<<<64, 256, 0, stream>>>(Gp, qp, zs, h, bias, abias, (float*)d_out);
}